// Round 10
// baseline (702.641 us; speedup 1.0000x reference)
//
#include <hip/hip_runtime.h>
#include <hip/hip_bf16.h>
#include <math.h>

#define B_   8
#define S_   2048
#define T_   (B_*S_)      // 16384 tokens
#define FIN  256
#define E_   512
#define H_   8
#define D_   64
#define FFN_ 2048
#define NC_  1000
#define NW_  8

typedef __attribute__((ext_vector_type(8))) short short8;
typedef __attribute__((ext_vector_type(4))) short short4v;
typedef __attribute__((ext_vector_type(4))) float f32x4;

__device__ __forceinline__ unsigned short f2bf(float f) {
    __hip_bfloat16 h = __float2bfloat16(f);
    return __builtin_bit_cast(unsigned short, h);
}
__device__ __forceinline__ float bf2f(unsigned short u) {
    return __builtin_bit_cast(float, (unsigned int)u << 16);
}

// async global->LDS, 16B per lane; LDS dest = wave-uniform base + lane*16
__device__ __forceinline__ void gld16(void* l, const void* g) {
    __builtin_amdgcn_global_load_lds(
        (const __attribute__((address_space(1))) unsigned int*)g,
        (__attribute__((address_space(3))) unsigned int*)l,
        16, 0, 0);
}

#if defined(__has_builtin)
#if __has_builtin(__builtin_amdgcn_mfma_f32_16x16x16bf16_1k)
#define HAVE_MFMA16 1
#endif
#endif

// K=16 bf16 MFMA (half-rate; used only in gemm_w2f where f-gen is cheap)
__device__ __forceinline__ f32x4 mfma16(short4v a, short4v b, f32x4 c) {
#ifdef HAVE_MFMA16
    return __builtin_amdgcn_mfma_f32_16x16x16bf16_1k(a, b, c, 0, 0, 0);
#else
    short8 a8 = {a[0], a[1], a[2], a[3], 0, 0, 0, 0};
    short8 b8 = {b[0], b[1], b[2], b[3], 0, 0, 0, 0};
    return __builtin_amdgcn_mfma_f32_16x16x32_bf16(a8, b8, c, 0, 0, 0);
#endif
}

// ---------------------------------------------------------------------------
// fp32 -> bf16 bulk conversion: x | Wi | Wo(2l) | W2(2l) | W1(2l).
// ---------------------------------------------------------------------------
__global__ __launch_bounds__(256)
void cvt_all(const float* __restrict__ x,  const float* __restrict__ Wi,
             const float* __restrict__ Wo, const float* __restrict__ W2,
             const float* __restrict__ W1,
             unsigned short* xb, unsigned short* Wib,
             unsigned short* Wob, unsigned short* W2b, unsigned short* W1b)
{
    int g = blockIdx.x*256 + threadIdx.x;
    const float* s; unsigned short* d; int o;
    if      (g < 1048576) { s = x;  d = xb;  o = g; }
    else if (g < 1081344) { s = Wi; d = Wib; o = g - 1048576; }
    else if (g < 1212416) { s = Wo; d = Wob; o = g - 1081344; }
    else if (g < 1736704) { s = W2; d = W2b; o = g - 1212416; }
    else                  { s = W1; d = W1b; o = g - 1736704; }
    float4 vv = ((const float4*)s)[o];
    ushort4 u;
    u.x = f2bf(vv.x); u.y = f2bf(vv.y); u.z = f2bf(vv.z); u.w = f2bf(vv.w);
    ((ushort4*)d)[o] = u;
}

// ---------------------------------------------------------------------------
// Weff[which][l][f][w] = scale * sum_e W[l][f][e] * Wproj[l][e][w]  -> bf16
// ---------------------------------------------------------------------------
__global__ __launch_bounds__(64)
void weff_kernel(const float* __restrict__ Wq, const float* __restrict__ Wk,
                 const float* __restrict__ Wv, const float* __restrict__ Wproj,
                 unsigned short* __restrict__ Weff)
{
    const int f = blockIdx.x, l = blockIdx.y, which = blockIdx.z;
    const int lane = threadIdx.x;
    const float* W = (which == 0 ? Wq : which == 1 ? Wk : Wv)
                     + (size_t)l*E_*E_ + (size_t)f*E_;
    const float* P = Wproj + (size_t)l*E_*NW_;
    const int wv = lane & 7;
    float s = 0.f;
    for (int e = (lane >> 3)*64; e < (lane >> 3)*64 + 64; e++)
        s += W[e] * P[e*NW_ + wv];
    #pragma unroll
    for (int off = 8; off < 64; off <<= 1) s += __shfl_xor(s, off);
    const float scale = (which == 0) ? 0.18033688011112042f : 1.f;
    if (lane < 8)
        Weff[((size_t)(which*2 + l)*E_ + f)*NW_ + lane] = f2bf(s * scale);
}

// ---------------------------------------------------------------------------
// q/k (row-major) and vT (transposed [head*64+d][s]) from cos-encoded h (bf16).
// ---------------------------------------------------------------------------
__global__ __launch_bounds__(256)
void qkv_small(const unsigned short* __restrict__ h, const float* __restrict__ theta,
               const unsigned short* __restrict__ Wq_e,
               const unsigned short* __restrict__ Wk_e,
               const unsigned short* __restrict__ Wv_e,
               unsigned short* __restrict__ qo, unsigned short* __restrict__ ko,
               unsigned short* __restrict__ vT)
{
    const int tid = threadIdx.x;
    const int t0 = blockIdx.x * 32;
    __shared__ float cs[32][8];
    {
        int tl = tid >> 3, wv2 = tid & 7;
        cs[tl][wv2] = cosf(bf2f(h[(size_t)(t0 + tl)*E_ + wv2]) + theta[wv2]);
    }
    __syncthreads();
    const int f = tid * 2;
    float wq[16], wk[16], wv_[16];
    #pragma unroll
    for (int i = 0; i < 16; i++) {
        wq[i]  = bf2f(Wq_e[(size_t)f*NW_ + i]);
        wk[i]  = bf2f(Wk_e[(size_t)f*NW_ + i]);
        wv_[i] = bf2f(Wv_e[(size_t)f*NW_ + i]);
    }
    unsigned int v0p[16] __attribute__((aligned(16)));
    unsigned int v1p[16] __attribute__((aligned(16)));
    for (int t = 0; t < 32; t++) {
        float4 c01 = *(const float4*)&cs[t][0];
        float4 c23 = *(const float4*)&cs[t][4];
        float c[8] = {c01.x,c01.y,c01.z,c01.w,c23.x,c23.y,c23.z,c23.w};
        float q0=0,q1=0,k0=0,k1=0,v0=0,v1=0;
        #pragma unroll
        for (int i = 0; i < 8; i++) {
            q0 += c[i]*wq[i];  q1 += c[i]*wq[8+i];
            k0 += c[i]*wk[i];  k1 += c[i]*wk[8+i];
            v0 += c[i]*wv_[i]; v1 += c[i]*wv_[8+i];
        }
        size_t base = (size_t)(t0 + t)*E_ + f;
        ushort2 uq; uq.x = f2bf(q0); uq.y = f2bf(q1);
        ushort2 uk; uk.x = f2bf(k0); uk.y = f2bf(k1);
        *(ushort2*)&qo[base] = uq;
        *(ushort2*)&ko[base] = uk;
        unsigned int b0 = f2bf(v0), b1 = f2bf(v1);
        if (t & 1) { v0p[t>>1] |= b0 << 16; v1p[t>>1] |= b1 << 16; }
        else       { v0p[t>>1]  = b0;       v1p[t>>1]  = b1; }
    }
    const int bb = t0 >> 11, s0 = t0 & (S_ - 1);
    const int head = f >> 6, d = f & 63;
    unsigned short* r0 = vT + ((size_t)(bb*H_ + head)*64 + d)*S_ + s0;
    #pragma unroll
    for (int c = 0; c < 4; c++) *(float4*)(r0 + c*8) = *(float4*)&v0p[c*4];
    r0 += S_;
    #pragma unroll
    for (int c = 0; c < 4; c++) *(float4*)(r0 + c*8) = *(float4*)&v1p[c*4];
}

// ---------------------------------------------------------------------------
// All-bf16 MFMA GEMM: C = scale*(A[M][K] * W[N][K]^T). 128x128 tile, BK=32,
// double-buffered gld16. XCD swizzle. MODE 1: += bias + posenc.
// ---------------------------------------------------------------------------
template<int TC_BF16, int MODE>
__global__ __launch_bounds__(256)
void gemm_mfma(const unsigned short* __restrict__ A,
               const unsigned short* __restrict__ Bm,
               void* __restrict__ Cv, int M, int N, int K,
               float scale, const float* __restrict__ bias)
{
    __shared__ unsigned short Al[2][128*32];
    __shared__ unsigned short Bl[2][128*32];
    const int tid  = threadIdx.x;
    const int lane = tid & 63;
    const int w    = tid >> 6;
    const int wx   = w & 1, wy = w >> 1;
    int bx, by;
    {
        int nx = gridDim.x;
        int bid = blockIdx.y * nx + blockIdx.x;
        int rpx = gridDim.y >> 3;
        int xcd = bid & 7, idx = bid >> 3;
        by = xcd * rpx + idx / nx;
        bx = idx % nx;
    }
    const int rowBase = by * 128;
    const int colBase = bx * 128;
    const int l15  = lane & 15;
    const int quad = lane >> 4;
    const int srow = lane >> 2;
    const int gch  = (lane & 3) ^ ((srow >> 1) & 3);
    const int swz  = (l15 >> 1) & 3;

    f32x4 acc[4][4] = {};

    #pragma unroll
    for (int it = 0; it < 2; it++) {
        int rb = it*64 + w*16;
        gld16(&Al[0][rb*32], A  + (size_t)(rowBase + rb + srow)*K + gch*8);
        gld16(&Bl[0][rb*32], Bm + (size_t)(colBase + rb + srow)*K + gch*8);
    }

    for (int k0 = 0; k0 < K; k0 += 32) {
        const int cur = (k0 >> 5) & 1;
        __syncthreads();
        if (k0 + 32 < K) {
            #pragma unroll
            for (int it = 0; it < 2; it++) {
                int rb = it*64 + w*16;
                gld16(&Al[1-cur][rb*32], A  + (size_t)(rowBase + rb + srow)*K + k0 + 32 + gch*8);
                gld16(&Bl[1-cur][rb*32], Bm + (size_t)(colBase + rb + srow)*K + k0 + 32 + gch*8);
            }
        }
        short8 af[4], bfr[4];
        #pragma unroll
        for (int mi = 0; mi < 4; mi++)
            af[mi] = *(const short8*)&Al[cur][(wy*64 + mi*16 + l15)*32 + ((quad ^ swz) << 3)];
        #pragma unroll
        for (int ni = 0; ni < 4; ni++)
            bfr[ni] = *(const short8*)&Bl[cur][(wx*64 + ni*16 + l15)*32 + ((quad ^ swz) << 3)];
        #pragma unroll
        for (int mi = 0; mi < 4; mi++)
            #pragma unroll
            for (int ni = 0; ni < 4; ni++)
                acc[mi][ni] = __builtin_amdgcn_mfma_f32_16x16x32_bf16(
                    af[mi], bfr[ni], acc[mi][ni], 0, 0, 0);
    }

    #pragma unroll
    for (int mi = 0; mi < 4; mi++) {
        #pragma unroll
        for (int ni = 0; ni < 4; ni++) {
            #pragma unroll
            for (int r = 0; r < 4; r++) {
                int row = rowBase + wy*64 + mi*16 + quad*4 + r;
                int col = colBase + wx*64 + ni*16 + l15;
                float v = acc[mi][ni][r] * scale;
                if (MODE == 1) {
                    int s = row & (S_ - 1);
                    float freq = __expf(-0.017988946039244957f * (float)(col & ~1));
                    float ang = (float)s * freq;
                    v += bias[col] + ((col & 1) ? cosf(ang) : sinf(ang));
                }
                if (TC_BF16) ((unsigned short*)Cv)[(size_t)row*N + col] = f2bf(v);
                else         ((float*)Cv)[(size_t)row*N + col] = v;
            }
        }
    }
}

// ---------------------------------------------------------------------------
// Fused ffn1 + W2 GEMM (h bf16): tmp^T = W2 . relu(W1 . cos8^T).
// ---------------------------------------------------------------------------
__global__ __launch_bounds__(256)
void gemm_w2f(const unsigned short* __restrict__ h, const float* __restrict__ phi,
              const unsigned short* __restrict__ W1b,   // [FFN][8] bf16
              const unsigned short* __restrict__ W2b,   // [E][FFN] bf16
              unsigned short* __restrict__ tmp)          // [T][E] bf16
{
    __shared__ char Lraw[17408];
    unsigned short* Wl = (unsigned short*)Lraw;   // [2][128*32]
    float* Ot = (float*)Lraw;                     // [128][33] epilogue

    const int tid  = threadIdx.x;
    const int lane = tid & 63;
    const int w    = tid >> 6;
    const int tx   = w & 1, ty = w >> 1;
    const int l15  = lane & 15;
    const int quad = lane >> 4;
    const int srow = lane >> 2;
    const int gch  = (lane & 3) ^ ((srow >> 1) & 3);
    const int swz  = (l15 >> 1) & 3;

    const int bid = blockIdx.x;
    const int xcd = bid & 7;
    const int eb  = xcd >> 1;
    const int tb  = (xcd & 1) * 64 + (bid >> 3);
    const int tBase = tb * 128;
    const int eBase = eb * 128;

    short4v cosfr[4];
    #pragma unroll
    for (int nt = 0; nt < 4; nt++) {
        short4v c = {0,0,0,0};
        if (quad < 2) {
            int tok = tBase + ty*64 + nt*16 + l15;
            #pragma unroll
            for (int i = 0; i < 4; i++) {
                int wv = quad*4 + i;
                c[i] = (short)f2bf(cosf(bf2f(h[(size_t)tok*E_ + wv]) + phi[wv]));
            }
        }
        cosfr[nt] = c;
    }

    #pragma unroll
    for (int it = 0; it < 2; it++) {
        int rb = w*32 + it*16;
        gld16(&Wl[rb*32], W2b + (size_t)(eBase + rb + srow)*FFN_ + gch*8);
    }
    short4v w1f[2] = {{0,0,0,0},{0,0,0,0}};
    #pragma unroll
    for (int jb = 0; jb < 2; jb++)
        if (quad < 2)
            w1f[jb] = *(const short4v*)&W1b[(size_t)(jb*16 + l15)*NW_ + quad*4];

    f32x4 acc[4][4] = {};   // acc[et][nt]: col=token(l15), row=e(quad*4+r)
    const f32x4 fzero = {0.f, 0.f, 0.f, 0.f};

    for (int k0 = 0; k0 < FFN_; k0 += 32) {
        const int cur = (k0 >> 5) & 1;
        __syncthreads();
        if (k0 + 32 < FFN_) {
            #pragma unroll
            for (int it = 0; it < 2; it++) {
                int rb = w*32 + it*16;
                gld16(&Wl[(1-cur)*4096 + rb*32],
                      W2b + (size_t)(eBase + rb + srow)*FFN_ + k0 + 32 + gch*8);
            }
        }
        short4v pf[4][2];
        #pragma unroll
        for (int nt = 0; nt < 4; nt++)
            #pragma unroll
            for (int jb = 0; jb < 2; jb++) {
                f32x4 c = mfma16(w1f[jb], cosfr[nt], fzero);
                short4v p;
                #pragma unroll
                for (int r = 0; r < 4; r++)
                    p[r] = (short)f2bf(fmaxf(c[r], 0.f));
                pf[nt][jb] = p;
            }
        if (k0 + 32 < FFN_) {
            #pragma unroll
            for (int jb = 0; jb < 2; jb++)
                if (quad < 2)
                    w1f[jb] = *(const short4v*)&W1b[(size_t)(k0 + 32 + jb*16 + l15)*NW_ + quad*4];
        }
        #pragma unroll
        for (int et = 0; et < 4; et++)
            #pragma unroll
            for (int jb = 0; jb < 2; jb++) {
                short4v wf = *(const short4v*)&Wl[cur*4096 + (tx*64 + et*16 + l15)*32
                               + (((jb*2 + (quad>>1)) ^ swz) << 3) + (quad & 1)*4];
                #pragma unroll
                for (int nt = 0; nt < 4; nt++)
                    acc[et][nt] = mfma16(wf, pf[nt][jb], acc[et][nt]);
            }
    }

    #pragma unroll
    for (int et = 0; et < 4; et++) {
        __syncthreads();
        #pragma unroll
        for (int nt = 0; nt < 4; nt++)
            #pragma unroll
            for (int r = 0; r < 4; r++)
                Ot[(ty*64 + nt*16 + l15)*33 + tx*16 + quad*4 + r] = acc[et][nt][r];
        __syncthreads();
        int token = tid >> 1, half = tid & 1;
        unsigned short u[16] __attribute__((aligned(16)));
        #pragma unroll
        for (int i = 0; i < 16; i++) u[i] = f2bf(Ot[token*33 + half*16 + i]);
        unsigned short* dst = tmp + (size_t)(tBase + token)*E_ + eBase + half*64 + et*16;
        *(float4*)dst       = *(float4*)&u[0];
        *(float4*)(dst + 8) = *(float4*)&u[8];
    }
}

// ---------------------------------------------------------------------------
// MFMA flash attention v6: S^T trick + K=32 PV via kv-permutation π.
// π(w,quad,j): j<4 -> kv=32w+quad*4+j (own pk[2w]); j>=4 ->
// kv=32w+16+(quad^1)*4+(j-4) (pk[2w+1] from lane^16). B-frag = 2 uints own +
// 2 shfl_xor(16). V^T A-frag = two b64 LDS reads at the same π offsets.
// Row-sums via ones-MFMA K=32 on the same fragments. XCD swizzle.
// ---------------------------------------------------------------------------
__global__ __launch_bounds__(256)
void flash_attn(const unsigned short* __restrict__ q,
                const unsigned short* __restrict__ k,
                const unsigned short* __restrict__ vT,
                unsigned short* __restrict__ o)
{
    __shared__ unsigned short L[17168];   // 34336 B
    unsigned short* Ks = L;               // [2][64*64]
    unsigned short* Vt = L + 8192;        // [2][64*64]  ([d][kv])
    float* Ot = (float*)L;                // epilogue [128][67]

    const int tid  = threadIdx.x;
    const int lane = tid & 63;
    const int w    = tid >> 6;
    const int l15  = lane & 15;
    const int quad = lane >> 4;
    const int bid  = blockIdx.x;
    const int xcd  = bid & 7;
    const int rest = bid >> 3;
    const int combo = xcd * 8 + (rest >> 4);
    const int qt = rest & 15;
    const int hh = combo & 7;
    const int bb = combo >> 3;
    const size_t qrow0 = (size_t)bb*S_ + (size_t)qt*128;
    const unsigned short* qp  = q  + qrow0*E_ + hh*64;
    const unsigned short* kp  = k  + ((size_t)bb*S_)*E_ + hh*64;
    const unsigned short* vtp = vT + (size_t)(bb*H_ + hh)*64*S_;

    const int srow8 = lane >> 3;
    const int gch8  = (lane & 7) ^ srow8;
    const int sql   = l15 & 7;

    #pragma unroll
    for (int it = 0; it < 4; it++) {
        int rb = it*32 + w*8;
        gld16(&L[rb*64], qp + (size_t)(rb + srow8)*E_ + gch8*8);
    }
    __syncthreads();
    short8 qfr[2][2];
    #pragma unroll
    for (int mi = 0; mi < 2; mi++)
        #pragma unroll
        for (int kc = 0; kc < 2; kc++)
            qfr[mi][kc] = *(const short8*)&L[(w*32 + mi*16 + l15)*64
                                             + (((kc*4 + quad) ^ sql) << 3)];
    __syncthreads();

    #pragma unroll
    for (int it = 0; it < 2; it++) {
        int rb = it*32 + w*8;
        gld16(&Ks[rb*64], kp  + (size_t)(rb + srow8)*E_ + gch8*8);
        gld16(&Vt[rb*64], vtp + (size_t)(rb + srow8)*S_ + gch8*8);
    }

    const short8 ones8 = {(short)0x3F80,(short)0x3F80,(short)0x3F80,(short)0x3F80,
                          (short)0x3F80,(short)0x3F80,(short)0x3F80,(short)0x3F80};
    f32x4 O[2][4] = {};
    f32x4 Ol[2]   = {};

    for (int kt = 0; kt < S_/64; kt++) {
        const int cur = kt & 1;
        __syncthreads();
        if (kt + 1 < S_/64) {
            #pragma unroll
            for (int it = 0; it < 2; it++) {
                int rb = it*32 + w*8;
                gld16(&Ks[(1-cur)*4096 + rb*64],
                      kp  + (size_t)((kt+1)*64 + rb + srow8)*E_ + gch8*8);
                gld16(&Vt[(1-cur)*4096 + rb*64],
                      vtp + (size_t)(rb + srow8)*S_ + (kt+1)*64 + gch8*8);
            }
        }
        // S^T: read kf once per (kc,nt), feed both mi
        f32x4 Sc[2][4] = {};
        #pragma unroll
        for (int kc = 0; kc < 2; kc++)
            #pragma unroll
            for (int nt = 0; nt < 4; nt++) {
                short8 kf = *(const short8*)&Ks[cur*4096 + (nt*16 + l15)*64
                                                 + (((kc*4 + quad) ^ sql) << 3)];
                Sc[0][nt] = __builtin_amdgcn_mfma_f32_16x16x32_bf16(kf, qfr[0][kc], Sc[0][nt], 0, 0, 0);
                Sc[1][nt] = __builtin_amdgcn_mfma_f32_16x16x32_bf16(kf, qfr[1][kc], Sc[1][nt], 0, 0, 0);
            }
        // exp2 -> packed bf16 pairs (own kv = nt*16 + quad*4 + r)
        unsigned pka[2][4], pkb[2][4];
        #pragma unroll
        for (int mi = 0; mi < 2; mi++)
            #pragma unroll
            for (int nt = 0; nt < 4; nt++) {
                unsigned b0 = f2bf(__builtin_amdgcn_exp2f(Sc[mi][nt][0]));
                unsigned b1 = f2bf(__builtin_amdgcn_exp2f(Sc[mi][nt][1]));
                unsigned b2 = f2bf(__builtin_amdgcn_exp2f(Sc[mi][nt][2]));
                unsigned b3 = f2bf(__builtin_amdgcn_exp2f(Sc[mi][nt][3]));
                pka[mi][nt] = b0 | (b1 << 16);
                pkb[mi][nt] = b2 | (b3 << 16);
            }
        // K=32 B-operand fragments via xor-16 exchange; row-sums via ones-MFMA
        short8 bw[2][2];
        #pragma unroll
        for (int mi = 0; mi < 2; mi++)
            #pragma unroll
            for (int w2 = 0; w2 < 2; w2++) {
                unsigned c0 = (unsigned)__shfl_xor((int)pka[mi][w2*2+1], 16);
                unsigned c1 = (unsigned)__shfl_xor((int)pkb[mi][w2*2+1], 16);
                uint4 u; u.x = pka[mi][w2*2]; u.y = pkb[mi][w2*2]; u.z = c0; u.w = c1;
                bw[mi][w2] = __builtin_bit_cast(short8, u);
                Ol[mi] = __builtin_amdgcn_mfma_f32_16x16x32_bf16(ones8, bw[mi][w2], Ol[mi], 0, 0, 0);
            }
        // O^T += V^T . P^T  (K=32, shared vf across mi)
        #pragma unroll
        for (int dt = 0; dt < 4; dt++) {
            const int rowb = cur*4096 + (dt*16 + l15)*64;
            #pragma unroll
            for (int w2 = 0; w2 < 2; w2++) {
                int c1 = 4*w2 + (quad >> 1);
                int o1 = ((c1 ^ sql) << 3) + (quad & 1)*4;
                int o2 = (((c1 + 2) ^ sql) << 3) + (((quad & 1) ^ 1))*4;
                short4v v0 = *(const short4v*)&Vt[rowb + o1];
                short4v v1 = *(const short4v*)&Vt[rowb + o2];
                short8 vf = {v0[0],v0[1],v0[2],v0[3],v1[0],v1[1],v1[2],v1[3]};
                O[0][dt] = __builtin_amdgcn_mfma_f32_16x16x32_bf16(vf, bw[0][w2], O[0][dt], 0, 0, 0);
                O[1][dt] = __builtin_amdgcn_mfma_f32_16x16x32_bf16(vf, bw[1][w2], O[1][dt], 0, 0, 0);
            }
        }
    }

    // Ol lane value = full row sum for q=l15 (all m-rows identical)
    __syncthreads();
    #pragma unroll
    for (int mi = 0; mi < 2; mi++) {
        float inv = 1.f / Ol[mi][0];
        #pragma unroll
        for (int dt = 0; dt < 4; dt++)
            #pragma unroll
            for (int r = 0; r < 4; r++)
                Ot[(w*32 + mi*16 + l15)*67 + dt*16 + quad*4 + r] = O[mi][dt][r] * inv;
    }
    __syncthreads();
    {
        int row = tid >> 1, half = tid & 1;
        unsigned short u[32] __attribute__((aligned(16)));
        #pragma unroll
        for (int i = 0; i < 32; i++) u[i] = f2bf(Ot[row*67 + half*32 + i]);
        unsigned short* dst = o + (qrow0 + row)*E_ + hh*64 + half*32;
        #pragma unroll
        for (int c = 0; c < 4; c++) *(float4*)(dst + c*8) = *(float4*)&u[c*8];
    }
}

// ---------------------------------------------------------------------------
// h = LayerNorm(h + delta) * g + b  (h bf16; one wave per token, no barriers)
// ---------------------------------------------------------------------------
__global__ __launch_bounds__(256)
void add_ln(unsigned short* __restrict__ h, const unsigned short* __restrict__ delta,
            const float* __restrict__ g, const float* __restrict__ b)
{
    const int lane = threadIdx.x & 63;
    const int t = blockIdx.x*4 + (threadIdx.x >> 6);
    const size_t base = (size_t)t*E_ + lane*8;
    uint4 hv = *(const uint4*)&h[base];
    uint4 dv = *(const uint4*)&delta[base];
    float x[8];
    #pragma unroll
    for (int i = 0; i < 4; i++) {
        unsigned hu = ((const unsigned*)&hv)[i], du = ((const unsigned*)&dv)[i];
        x[2*i]   = bf2f((unsigned short)(hu & 0xffff)) + bf2f((unsigned short)(du & 0xffff));
        x[2*i+1] = bf2f((unsigned short)(hu >> 16))    + bf2f((unsigned short)(du >> 16));
    }
    float s = 0.f, sq = 0.f;
    #pragma unroll
    for (int i = 0; i < 8; i++) { s += x[i]; sq += x[i]*x[i]; }
    #pragma unroll
    for (int off = 1; off < 64; off <<= 1) {
        s  += __shfl_xor(s,  off);
        sq += __shfl_xor(sq, off);
    }
    float mu  = s * (1.f/E_);
    float var = sq * (1.f/E_) - mu*mu;
    float rstd = rsqrtf(var + 1e-5f);
    float4 g0 = *(const float4*)&g[lane*8], g1 = *(const float4*)&g[lane*8 + 4];
    float4 b0 = *(const float4*)&b[lane*8], b1 = *(const float4*)&b[lane*8 + 4];
    float gg[8] = {g0.x,g0.y,g0.z,g0.w,g1.x,g1.y,g1.z,g1.w};
    float bb[8] = {b0.x,b0.y,b0.z,b0.w,b1.x,b1.y,b1.z,b1.w};
    uint4 ov;
    #pragma unroll
    for (int i = 0; i < 4; i++) {
        unsigned lo = f2bf((x[2*i]   - mu)*rstd*gg[2*i]   + bb[2*i]);
        unsigned hi = f2bf((x[2*i+1] - mu)*rstd*gg[2*i+1] + bb[2*i+1]);
        ((unsigned*)&ov)[i] = lo | (hi << 16);
    }
    *(uint4*)&h[base] = ov;
}

__global__ __launch_bounds__(256)
void pool_partial(const unsigned short* __restrict__ h, float* __restrict__ part)
{
    const int chunk = blockIdx.x, bb = blockIdx.y, tid = threadIdx.x;
    for (int e = tid; e < E_; e += 256) {
        const unsigned short* p = h + ((size_t)bb*S_ + (size_t)chunk*128)*E_ + e;
        float s = 0.f;
        for (int r = 0; r < 128; r++) s += bf2f(p[(size_t)r*E_]);
        part[(size_t)(bb*16 + chunk)*E_ + e] = s;
    }
}

__global__ __launch_bounds__(256)
void pool_final(const float* __restrict__ part, float* __restrict__ pooled)
{
    const int bb = blockIdx.x, tid = threadIdx.x;
    for (int e = tid; e < E_; e += 256) {
        float s = 0.f;
        #pragma unroll
        for (int c = 0; c < 16; c++) s += part[(size_t)(bb*16 + c)*E_ + e];
        pooled[bb*E_ + e] = s * (1.f/S_);
    }
}

__global__ __launch_bounds__(64)
void classify(const float* __restrict__ pooled, const float* __restrict__ Wc,
              const float* __restrict__ bc, float* __restrict__ out)
{
    const int c = blockIdx.x, bb = blockIdx.y, lane = threadIdx.x;
    const float* p = pooled + bb*E_;
    const float* wc = Wc + (size_t)c*E_;
    float s = 0.f;
    for (int e = lane; e < E_; e += 64) s += p[e]*wc[e];
    #pragma unroll
    for (int off = 1; off < 64; off <<= 1) s += __shfl_xor(s, off);
    if (lane == 0) out[bb*NC_ + c] = s + bc[c];
}

// ---------------------------------------------------------------------------
extern "C" void kernel_launch(void* const* d_in, const int* in_sizes, int n_in,
                              void* d_out, int out_size, void* d_ws, size_t ws_size,
                              hipStream_t stream)
{
    const float* x       = (const float*)d_in[0];
    const float* Wi      = (const float*)d_in[1];
    const float* bi      = (const float*)d_in[2];
    const float* theta_a = (const float*)d_in[3];
    const float* Wproj   = (const float*)d_in[4];
    const float* Wq      = (const float*)d_in[5];
    const float* Wk      = (const float*)d_in[6];
    const float* Wv      = (const float*)d_in[7];
    const float* Wo      = (const float*)d_in[8];
    const float* g1      = (const float*)d_in[9];
    const float* b1      = (const float*)d_in[10];
    const float* phi     = (const float*)d_in[11];
    const float* W1      = (const float*)d_in[12];
    const float* W2      = (const float*)d_in[13];
    const float* g2      = (const float*)d_in[14];
    const float* b2      = (const float*)d_in[15];
    const float* Wc      = (const float*)d_in[16];
    const float* bc      = (const float*)d_in[17];
    float* out = (float*)d_out;

    char* ws = (char*)d_ws;
    const size_t MB = 1024u*1024u;
    unsigned short* h      = (unsigned short*)(ws + 0*MB);    // 16 MB bf16
    unsigned short* tmp    = (unsigned short*)(ws + 16*MB);   // 16 MB bf16
    unsigned short* qb     = (unsigned short*)(ws + 32*MB);   // 16 MB
    unsigned short* kb     = (unsigned short*)(ws + 48*MB);   // 16 MB
    unsigned short* vT     = (unsigned short*)(ws + 64*MB);   // 16 MB
    unsigned short* ao     = (unsigned short*)(ws + 80*MB);   // 16 MB
    unsigned short* xb     = (unsigned short*)(ws + 96*MB);   // 8 MB
    unsigned short* Wib    = (unsigned short*)(ws + 104*MB);  // 256 KB
    unsigned short* Wob    = (unsigned short*)(ws + 105*MB);  // 1 MB (both layers)
    unsigned short* W2b    = (unsigned short*)(ws + 106*MB);  // 4 MB (both layers)
    unsigned short* W1b    = (unsigned short*)(ws + 110*MB);  // 64 KB (both layers)
    unsigned short* Weff   = (unsigned short*)(ws + 111*MB);  // 48 KB
    float*          part   = (float*)(ws + 112*MB);           // 256 KB
    float*          pooled = (float*)(ws + 112*MB + 512*1024);

    // 0. bulk fp32->bf16 conversion + effective QKV weights
    cvt_all<<<6816, 256, 0, stream>>>(x, Wi, Wo, W2, W1, xb, Wib, Wob, W2b, W1b);
    weff_kernel<<<dim3(E_, 2, 3), 64, 0, stream>>>(Wq, Wk, Wv, Wproj, Weff);

    // 1. h = x @ Wi^T + bi + posenc  (bf16 h)
    gemm_mfma<1,1><<<dim3(E_/128, T_/128), 256, 0, stream>>>(
        xb, Wib, h, T_, E_, FIN, 1.f, bi);

    for (int l = 0; l < 2; l++) {
        const unsigned short* Wq_e = Weff + (size_t)(0*2 + l)*E_*NW_;
        const unsigned short* Wk_e = Weff + (size_t)(1*2 + l)*E_*NW_;
        const unsigned short* Wv_e = Weff + (size_t)(2*2 + l)*E_*NW_;
        // quantum attention sublayer
        qkv_small<<<T_/32, 256, 0, stream>>>(h, theta_a + l*NW_, Wq_e, Wk_e, Wv_e, qb, kb, vT);
        flash_attn<<<(S_/128)*H_*B_, 256, 0, stream>>>(qb, kb, vT, ao);
        gemm_mfma<1,0><<<dim3(E_/128, T_/128), 256, 0, stream>>>(
            ao, Wob + (size_t)l*E_*E_, tmp, T_, E_, E_, 1.f, nullptr);
        add_ln<<<T_/4, 256, 0, stream>>>(h, tmp, g1 + l*E_, b1 + l*E_);

        // quantum feed-forward sublayer (fused ffn1 + W2)
        gemm_w2f<<<512, 256, 0, stream>>>(h, phi + l*NW_,
                                          W1b + (size_t)l*FFN_*NW_,
                                          W2b + (size_t)l*E_*FFN_, tmp);
        add_ln<<<T_/4, 256, 0, stream>>>(h, tmp, g2 + l*E_, b2 + l*E_);
    }

    // pooled mean over seq, then classifier
    pool_partial<<<dim3(16, B_), 256, 0, stream>>>(h, part);
    pool_final<<<B_, 256, 0, stream>>>(part, pooled);
    classify<<<dim3(NC_, B_), 64, 0, stream>>>(pooled, Wc, bc, out);
}